// Round 5
// baseline (364.062 us; speedup 1.0000x reference)
//
#include <hip/hip_runtime.h>

#define NB 32
#define NS 2048
#define ND 512
#define NA 64
#define NE 64

typedef __bf16 bf16x8 __attribute__((ext_vector_type(8)));
typedef __bf16 bf16x2 __attribute__((ext_vector_type(2)));
typedef float f32x4 __attribute__((ext_vector_type(4)));

__device__ __forceinline__ unsigned short f2bf(float f) {
    union { float f; unsigned u; } v; v.f = f;
    unsigned r = (v.u + 0x7fffu + ((v.u >> 16) & 1u)) >> 16;
    return (unsigned short)r;
}
// native RNE pack (v_cvt_pk_bf16_f32) -- bit-identical to f2bf for normals
__device__ __forceinline__ unsigned pk2(float lo, float hi) {
    bf16x2 t; t[0] = (__bf16)lo; t[1] = (__bf16)hi;
    return __builtin_bit_cast(unsigned, t);
}
__device__ __forceinline__ unsigned short f2bfn(float f) {
    __bf16 h = (__bf16)f; return __builtin_bit_cast(unsigned short, h);
}

// LDS-drain + barrier; vmcnt stays OUTSTANDING across it.
#define BAR() do { asm volatile("s_waitcnt lgkmcnt(0)" ::: "memory"); \
                   __builtin_amdgcn_s_barrier(); } while (0)
// full drain (vm + lgkm) + barrier: used once per tile end.
#define BARVM() do { asm volatile("s_waitcnt vmcnt(0) lgkmcnt(0)" ::: "memory"); \
                     __builtin_amdgcn_s_barrier(); } while (0)

// ---------------------------------------------------------------------------
// Kernel 1b (runs FIRST): the six small per-sample vectors, per b:
// [pre_w 512][pre_b 512][post_w 512][post_b 512][b_up 512][b_down 64] = 2624
// ---------------------------------------------------------------------------
__global__ __launch_bounds__(256) void hyper_vec(
    const float* __restrict__ emb,
    const float* __restrict__ pwW, const float* __restrict__ pwb,
    const float* __restrict__ pbW, const float* __restrict__ pbb,
    const float* __restrict__ powW, const float* __restrict__ powb,
    const float* __restrict__ pobW, const float* __restrict__ pobb,
    const float* __restrict__ ubW, const float* __restrict__ ubb,
    const float* __restrict__ dbW, const float* __restrict__ dbb,
    float* __restrict__ vecs) {
    int gid = blockIdx.x * 256 + threadIdx.x;
    if (gid >= NB * 2624) return;
    int b = gid / 2624;
    int r = gid - b * 2624;
    const float* W; const float* bias; int off, width;
    if (r < 2560) {
        int v = r >> 9; off = r & 511; width = 512;
        switch (v) {
            case 0:  W = pwW;  bias = pwb;  break;
            case 1:  W = pbW;  bias = pbb;  break;
            case 2:  W = powW; bias = powb; break;
            case 3:  W = pobW; bias = pobb; break;
            default: W = ubW;  bias = ubb;  break;
        }
    } else {
        off = r - 2560; width = 64; W = dbW; bias = dbb;
    }
    float acc = bias[off];
    const float* e = emb + b * 64;
#pragma unroll 8
    for (int k = 0; k < 64; ++k) acc = fmaf(e[k], W[k * width + off], acc);
    vecs[gid] = acc;
}

// ---------------------------------------------------------------------------
// Kernel 1a: hypernet big GEMMs emb[32,64] @ W[64,32768] -> bf16 frags.
// (unchanged from round 0)
// ---------------------------------------------------------------------------
__global__ __launch_bounds__(256) void hyper_pack(
    const float* __restrict__ emb,
    const float* __restrict__ dwW, const float* __restrict__ dwb,
    const float* __restrict__ uwW, const float* __restrict__ uwb,
    const float* __restrict__ vecs,
    unsigned short* __restrict__ wdfrag, unsigned short* __restrict__ wufrag,
    float* __restrict__ cvec) {
    __shared__ float Wt[64][128];
    __shared__ float embs[NB * NE];
    const int tid = threadIdx.x;
    const int lane = tid & 63;
    const int bx = blockIdx.x;
    const int mat = bx >> 8;
    const int chunk = bx & 255;
    const int base = chunk * 128;
    const int colo = tid & 127;
    const int bh = tid >> 7;            // 0 or 1: b-range [16*bh, 16*bh+16)
    const float* W = mat ? uwW : dwW;
    const float* bias = mat ? uwb : dwb;

    for (int i = tid; i < NB * NE; i += 256) embs[i] = emb[i];
    for (int i = tid; i < 64 * 32; i += 256) {
        int k = i >> 5, c = (i & 31) << 2;
        *(float4*)&Wt[k][c] = *(const float4*)&W[(size_t)k * 32768 + base + c];
    }
    __syncthreads();

    const int col = base + colo;
    const float bv = bias[col];
    float acc[16];
#pragma unroll
    for (int b = 0; b < 16; ++b) acc[b] = bv;

    for (int k0 = 0; k0 < 64; k0 += 4) {
        float w0 = Wt[k0][colo], w1 = Wt[k0 + 1][colo];
        float w2 = Wt[k0 + 2][colo], w3 = Wt[k0 + 3][colo];
#pragma unroll
        for (int b = 0; b < 16; ++b) {
            float4 e = *(const float4*)&embs[(bh * 16 + b) * 64 + k0];
            acc[b] = fmaf(e.x, w0, acc[b]);
            acc[b] = fmaf(e.y, w1, acc[b]);
            acc[b] = fmaf(e.z, w2, acc[b]);
            acc[b] = fmaf(e.w, w3, acc[b]);
        }
    }

    if (mat == 0) {
        int a = col >> 9, d = col & 511;   // a uniform per block (128 | 512)
        size_t idx0 = ((size_t)((a >> 4) * 16 + (d >> 5)) * 64 +
                       (((d & 31) >> 3) * 16 + (a & 15))) * 8 + (d & 7);
#pragma unroll
        for (int b = 0; b < 16; ++b) {
            int bg = bh * 16 + b;
            float raw = acc[b];
            float pw = vecs[bg * 2624 + d];
            float pb = vecs[bg * 2624 + 512 + d];
            float f = raw * pw;
            wdfrag[idx0 + (size_t)bg * 32768] = f2bf(f);
            float c2v = f, c1v = raw * pb;
#pragma unroll
            for (int m = 1; m <= 32; m <<= 1) {
                c2v += __shfl_xor(c2v, m);
                c1v += __shfl_xor(c1v, m);
            }
            if (lane == 0) {
                atomicAdd(&cvec[bg * 128 + 2 * a], c1v);
                atomicAdd(&cvec[bg * 128 + 2 * a + 1], c2v);
            }
        }
    } else {
        int d = col >> 6, a = col & 63;
        size_t idx0 = ((size_t)((d >> 4) * 2 + (a >> 5)) * 64 +
                       (((a & 31) >> 3) * 16 + (d & 15))) * 8 + (a & 7);
#pragma unroll
        for (int b = 0; b < 16; ++b)
            wufrag[idx0 + (size_t)(bh * 16 + b) * 32768] = f2bf(acc[b]);
    }
}

// ---------------------------------------------------------------------------
// Kernel 2 (round-5): DMA-streamed fused adapter.
// 512 blocks (exactly 2/CU), each owns 128 rows of one b = 8 tiles of 16.
// Input tiles are staged HBM->LDS by __builtin_amdgcn_global_load_lds into
// two f32 buffers x0/x1 ([16][516], +4-float row pad = bank-floor reads),
// issued TWO tiles ahead (zero VGPR cost -- the R1/R3 spill killer removed).
// Per tile: down-GEMM reads x from LDS, packs bf16 on the fly and computes
// LN stats concurrently (pre-LN fold => stats applied post-MFMA); residual
// read exactly (f32) from the same buffer => inp touched once from HBM.
// One vmcnt(0) per tile end waits on just-issued stores + a DMA that had a
// full tile of compute to land; the next DMA is issued right after.
// ---------------------------------------------------------------------------
__global__ __launch_bounds__(256, 2) void fused_adapter(
    const float* __restrict__ inp,
    const unsigned short* __restrict__ wdfold,
    const unsigned short* __restrict__ wufrag,
    const float* __restrict__ vecs,
    const float* __restrict__ cvec,
    float* __restrict__ out) {
    __shared__ __align__(16) float x0_lds[16 * 516];
    __shared__ __align__(16) float x1_lds[16 * 516];
    __shared__ __align__(16) unsigned short mid_lds[16][72];
    __shared__ __align__(16) float postS[16][4], postQ[16][4];

    const int tid = threadIdx.x;
    const int lane = tid & 63;
    const int wave = tid >> 6;
    const int lanelo = lane & 15;
    const int quad = lane >> 4;
    // bijective XCD swizzle: 512 blocks, XCD x owns [64x, 64x+64) = 4 b's.
    const int bx0 = blockIdx.x;
    const int bx = (bx0 & 7) * 64 + (bx0 >> 3);
    const int b = bx >> 4;
    const int sgrp = (bx & 15) * 128;    // 128 rows = 8 tiles per block

    const float* vb = vecs + b * 2624;
    const unsigned short* wd = wdfold + (size_t)b * 32768;
    const unsigned short* wu = wufrag + (size_t)b * 32768;

    // ---- DMA: tile t (16 rows x 512 f32) -> LDS buffer, wave w rows 4w..4w+3
    auto dma = [&](int t, float* xb) {
        const float* src = inp + ((size_t)b * NS + sgrp + t * 16 + wave * 4) * ND
                           + lane * 4;                    // per-lane 16 B
        float* dst = xb + (wave * 4) * 516;               // wave-uniform
#pragma unroll
        for (int rr = 0; rr < 4; ++rr) {
#pragma unroll
            for (int h = 0; h < 2; ++h) {
                __builtin_amdgcn_global_load_lds(
                    (const __attribute__((address_space(1))) void*)(src + rr * ND + h * 256),
                    (__attribute__((address_space(3))) void*)(dst + rr * 516 + h * 256),
                    16, 0, 0);
            }
        }
    };

    // ---- prologue: tiles 0,1 in flight; block-invariant scalars to regs ----
    dma(0, x0_lds);
    dma(1, x1_lds);
    float pw8[8], pb8[8], bu8[8];
#pragma unroll
    for (int i = 0; i < 8; ++i) {
        int col = (wave * 8 + i) * 16 + lanelo;
        pw8[i] = vb[1024 + col];    // post_w
        pb8[i] = vb[1536 + col];    // post_b
        bu8[i] = vb[2048 + col];    // b_up
    }
    const int a_col = wave * 16 + lanelo;
    const float2 cc = *(const float2*)(cvec + b * 128 + 2 * a_col);
    const float c1 = cc.x + vb[2560 + a_col];
    asm volatile("s_waitcnt vmcnt(0)" ::: "memory");
    __builtin_amdgcn_s_barrier();   // tiles 0,1 + scalars resident

    auto tile = [&](int t, float* xc) {
        // ---- phase B: down GEMM + on-the-fly bf16 pack + LN stats ----
        float s = 0.f, q = 0.f;
        f32x4 accd = (f32x4){0.f, 0.f, 0.f, 0.f};
#pragma unroll
        for (int kc = 0; kc < 16; ++kc) {
            const float* xr = xc + lanelo * 516 + kc * 32 + quad * 8;
            f32x4 xa = *(const f32x4*)xr;
            f32x4 xb = *(const f32x4*)(xr + 4);
            s += (xa[0] + xa[1]) + (xa[2] + xa[3]) + (xb[0] + xb[1]) + (xb[2] + xb[3]);
            q = fmaf(xa[0], xa[0], q); q = fmaf(xa[1], xa[1], q);
            q = fmaf(xa[2], xa[2], q); q = fmaf(xa[3], xa[3], q);
            q = fmaf(xb[0], xb[0], q); q = fmaf(xb[1], xb[1], q);
            q = fmaf(xb[2], xb[2], q); q = fmaf(xb[3], xb[3], q);
            uint4 au;
            au.x = pk2(xa[0], xa[1]); au.y = pk2(xa[2], xa[3]);
            au.z = pk2(xb[0], xb[1]); au.w = pk2(xb[2], xb[3]);
            uint4 bv = *(const uint4*)(wd + ((size_t)(wave * 16 + kc) * 64 + lane) * 8);
            accd = __builtin_amdgcn_mfma_f32_16x16x32_bf16(
                __builtin_bit_cast(bf16x8, au), __builtin_bit_cast(bf16x8, bv), accd, 0, 0, 0);
        }
        // full-row stats: quad-reduce within wave (each wave reads all cols)
        s += __shfl_xor(s, 16); s += __shfl_xor(s, 32);
        q += __shfl_xor(q, 16); q += __shfl_xor(q, 32);
        float mean = s * (1.0f / 512.0f);
        float var = q * (1.0f / 512.0f) - mean * mean;
        float rstd = rsqrtf(var + 1e-5f);
        float mrsl = mean * rstd;          // stats for row `lanelo`
#pragma unroll
        for (int r = 0; r < 4; ++r) {
            float rsr = __shfl(rstd, quad * 4 + r);
            float mrr = __shfl(mrsl, quad * 4 + r);
            float v = fmaf(rsr, accd[r], fmaf(-mrr, cc.y, c1));
            mid_lds[quad * 4 + r][a_col] = f2bfn(fmaxf(v, 0.0f));
        }
        BAR();   // mid visible

        // ---- phase C: up GEMM, wave w -> cols [128w,128w+128), acc[8] ----
        uint4 a0u = *(const uint4*)&mid_lds[lanelo][quad * 8];
        uint4 a1u = *(const uint4*)&mid_lds[lanelo][32 + quad * 8];
        bf16x8 af0 = __builtin_bit_cast(bf16x8, a0u);
        bf16x8 af1 = __builtin_bit_cast(bf16x8, a1u);
        f32x4 acc8[8];
        float sum[4] = {0.f, 0.f, 0.f, 0.f}, sq[4] = {0.f, 0.f, 0.f, 0.f};
#pragma unroll
        for (int nt8 = 0; nt8 < 8; ++nt8) {
            int nt = wave * 8 + nt8;
            uint4 b0 = *(const uint4*)(wu + ((size_t)(nt * 2 + 0) * 64 + lane) * 8);
            uint4 b1 = *(const uint4*)(wu + ((size_t)(nt * 2 + 1) * 64 + lane) * 8);
            f32x4 a4 = (f32x4){0.f, 0.f, 0.f, 0.f};
            a4 = __builtin_amdgcn_mfma_f32_16x16x32_bf16(af0, __builtin_bit_cast(bf16x8, b0), a4, 0, 0, 0);
            a4 = __builtin_amdgcn_mfma_f32_16x16x32_bf16(af1, __builtin_bit_cast(bf16x8, b1), a4, 0, 0, 0);
            float buv = bu8[nt8];
#pragma unroll
            for (int r = 0; r < 4; ++r) {
                float y = a4[r] + buv;
                a4[r] = y;
                sum[r] += y;
                sq[r] = fmaf(y, y, sq[r]);
            }
            acc8[nt8] = a4;
        }
#pragma unroll
        for (int r = 0; r < 4; ++r) {
#pragma unroll
            for (int m = 1; m <= 8; m <<= 1) {
                sum[r] += __shfl_xor(sum[r], m);
                sq[r] += __shfl_xor(sq[r], m);
            }
        }
        if (lanelo == 0) {
#pragma unroll
            for (int r = 0; r < 4; ++r) {
                postS[quad * 4 + r][wave] = sum[r];
                postQ[quad * 4 + r][wave] = sq[r];
            }
        }
        BAR();   // post-stat partials visible

        float mean2[4], rstd2[4];
#pragma unroll
        for (int r = 0; r < 4; ++r) {
            int row = quad * 4 + r;
            float4 S = *(const float4*)postS[row];
            float4 Q = *(const float4*)postQ[row];
            float ss = (S.x + S.y) + (S.z + S.w);
            float qq = (Q.x + Q.y) + (Q.z + Q.w);
            mean2[r] = ss * (1.0f / 512.0f);
            float v2 = qq * (1.0f / 512.0f) - mean2[r] * mean2[r];
            rstd2[r] = rsqrtf(v2 + 1e-5f);
        }

        // ---- epilogue: post-LN affine + exact f32 residual from LDS ----
        const size_t obase = ((size_t)b * NS + sgrp + t * 16) * ND;
#pragma unroll
        for (int nt8 = 0; nt8 < 8; ++nt8) {
            int col = (wave * 8 + nt8) * 16 + lanelo;
#pragma unroll
            for (int r = 0; r < 4; ++r) {
                size_t off = obase + (size_t)(quad * 4 + r) * ND + col;
                float xres = xc[(quad * 4 + r) * 516 + col];
                out[off] = fmaf((acc8[nt8][r] - mean2[r]) * rstd2[r],
                                pw8[nt8], pb8[nt8]) + xres;
            }
        }
        // tile end: stores acked, DMA(t+1) guaranteed landed, LDS reads done
        BARVM();
        if (t < 6) dma(t + 2, xc);   // buffer now free; 2-tiles-ahead prefetch
    };

#pragma unroll 1
    for (int tt = 0; tt < 8; tt += 2) {
        tile(tt, x0_lds);
        tile(tt + 1, x1_lds);
    }
}

// ---------------------------------------------------------------------------
extern "C" void kernel_launch(void* const* d_in, const int* in_sizes, int n_in,
                              void* d_out, int out_size, void* d_ws, size_t ws_size,
                              hipStream_t stream) {
    const float* emb  = (const float*)d_in[0];
    const float* inp  = (const float*)d_in[1];
    const float* dwW  = (const float*)d_in[2];
    const float* dwb  = (const float*)d_in[3];
    const float* dbW  = (const float*)d_in[4];
    const float* dbb  = (const float*)d_in[5];
    const float* uwW  = (const float*)d_in[6];
    const float* uwb  = (const float*)d_in[7];
    const float* ubW  = (const float*)d_in[8];
    const float* ubb  = (const float*)d_in[9];
    const float* pwW  = (const float*)d_in[10];
    const float* pwb  = (const float*)d_in[11];
    const float* pbW  = (const float*)d_in[12];
    const float* pbb  = (const float*)d_in[13];
    const float* powW = (const float*)d_in[14];
    const float* powb = (const float*)d_in[15];
    const float* pobW = (const float*)d_in[16];
    const float* pobb = (const float*)d_in[17];

    unsigned short* wdfrag = (unsigned short*)d_ws;
    unsigned short* wufrag = wdfrag + (size_t)NB * 32768;
    float* vecs = (float*)(wufrag + (size_t)NB * 32768);
    float* cvec = vecs + (size_t)NB * 2624;

    hyper_vec<<<(NB * 2624 + 255) / 256, 256, 0, stream>>>(
        emb, pwW, pwb, pbW, pbb, powW, powb, pobW, pobb, ubW, ubb, dbW, dbb, vecs);
    hipMemsetAsync(cvec, 0, (size_t)NB * 128 * sizeof(float), stream);
    hyper_pack<<<512, 256, 0, stream>>>(emb, dwW, dwb, uwW, uwb, vecs,
                                        wdfrag, wufrag, cvec);
    fused_adapter<<<512, 256, 0, stream>>>(
        inp, wdfrag, wufrag, vecs, cvec, (float*)d_out);
}

// Round 6
// 361.900 us; speedup vs baseline: 1.0060x; 1.0060x over previous
//
#include <hip/hip_runtime.h>

#define NB 32
#define NS 2048
#define ND 512
#define NA 64
#define NE 64

typedef __bf16 bf16x8 __attribute__((ext_vector_type(8)));
typedef float f32x4 __attribute__((ext_vector_type(4)));

__device__ __forceinline__ unsigned short f2bf(float f) {
    union { float f; unsigned u; } v; v.f = f;
    unsigned r = (v.u + 0x7fffu + ((v.u >> 16) & 1u)) >> 16;
    return (unsigned short)r;
}
__device__ __forceinline__ unsigned pk(float a, float b) {
    return (unsigned)f2bf(a) | ((unsigned)f2bf(b) << 16);
}

// LDS-drain + barrier; vmcnt stays OUTSTANDING across it (prefetch survives).
// Correctness validated in R2/R3/R5 (all passed with this barrier).
#define BAR() do { asm volatile("s_waitcnt lgkmcnt(0)" ::: "memory"); \
                   __builtin_amdgcn_s_barrier(); } while (0)

// ---------------------------------------------------------------------------
// Kernel 1b (runs FIRST): the six small per-sample vectors, per b:
// [pre_w 512][pre_b 512][post_w 512][post_b 512][b_up 512][b_down 64] = 2624
// ---------------------------------------------------------------------------
__global__ __launch_bounds__(256) void hyper_vec(
    const float* __restrict__ emb,
    const float* __restrict__ pwW, const float* __restrict__ pwb,
    const float* __restrict__ pbW, const float* __restrict__ pbb,
    const float* __restrict__ powW, const float* __restrict__ powb,
    const float* __restrict__ pobW, const float* __restrict__ pobb,
    const float* __restrict__ ubW, const float* __restrict__ ubb,
    const float* __restrict__ dbW, const float* __restrict__ dbb,
    float* __restrict__ vecs) {
    int gid = blockIdx.x * 256 + threadIdx.x;
    if (gid >= NB * 2624) return;
    int b = gid / 2624;
    int r = gid - b * 2624;
    const float* W; const float* bias; int off, width;
    if (r < 2560) {
        int v = r >> 9; off = r & 511; width = 512;
        switch (v) {
            case 0:  W = pwW;  bias = pwb;  break;
            case 1:  W = pbW;  bias = pbb;  break;
            case 2:  W = powW; bias = powb; break;
            case 3:  W = pobW; bias = pobb; break;
            default: W = ubW;  bias = ubb;  break;
        }
    } else {
        off = r - 2560; width = 64; W = dbW; bias = dbb;
    }
    float acc = bias[off];
    const float* e = emb + b * 64;
#pragma unroll 8
    for (int k = 0; k < 64; ++k) acc = fmaf(e[k], W[k * width + off], acc);
    vecs[gid] = acc;
}

// ---------------------------------------------------------------------------
// Kernel 1a: hypernet big GEMMs emb[32,64] @ W[64,32768] -> bf16 frags.
// (unchanged from round 0)
// ---------------------------------------------------------------------------
__global__ __launch_bounds__(256) void hyper_pack(
    const float* __restrict__ emb,
    const float* __restrict__ dwW, const float* __restrict__ dwb,
    const float* __restrict__ uwW, const float* __restrict__ uwb,
    const float* __restrict__ vecs,
    unsigned short* __restrict__ wdfrag, unsigned short* __restrict__ wufrag,
    float* __restrict__ cvec) {
    __shared__ float Wt[64][128];
    __shared__ float embs[NB * NE];
    const int tid = threadIdx.x;
    const int lane = tid & 63;
    const int bx = blockIdx.x;
    const int mat = bx >> 8;
    const int chunk = bx & 255;
    const int base = chunk * 128;
    const int colo = tid & 127;
    const int bh = tid >> 7;            // 0 or 1: b-range [16*bh, 16*bh+16)
    const float* W = mat ? uwW : dwW;
    const float* bias = mat ? uwb : dwb;

    for (int i = tid; i < NB * NE; i += 256) embs[i] = emb[i];
    for (int i = tid; i < 64 * 32; i += 256) {
        int k = i >> 5, c = (i & 31) << 2;
        *(float4*)&Wt[k][c] = *(const float4*)&W[(size_t)k * 32768 + base + c];
    }
    __syncthreads();

    const int col = base + colo;
    const float bv = bias[col];
    float acc[16];
#pragma unroll
    for (int b = 0; b < 16; ++b) acc[b] = bv;

    for (int k0 = 0; k0 < 64; k0 += 4) {
        float w0 = Wt[k0][colo], w1 = Wt[k0 + 1][colo];
        float w2 = Wt[k0 + 2][colo], w3 = Wt[k0 + 3][colo];
#pragma unroll
        for (int b = 0; b < 16; ++b) {
            float4 e = *(const float4*)&embs[(bh * 16 + b) * 64 + k0];
            acc[b] = fmaf(e.x, w0, acc[b]);
            acc[b] = fmaf(e.y, w1, acc[b]);
            acc[b] = fmaf(e.z, w2, acc[b]);
            acc[b] = fmaf(e.w, w3, acc[b]);
        }
    }

    if (mat == 0) {
        int a = col >> 9, d = col & 511;   // a uniform per block (128 | 512)
        size_t idx0 = ((size_t)((a >> 4) * 16 + (d >> 5)) * 64 +
                       (((d & 31) >> 3) * 16 + (a & 15))) * 8 + (d & 7);
#pragma unroll
        for (int b = 0; b < 16; ++b) {
            int bg = bh * 16 + b;
            float raw = acc[b];
            float pw = vecs[bg * 2624 + d];
            float pb = vecs[bg * 2624 + 512 + d];
            float f = raw * pw;
            wdfrag[idx0 + (size_t)bg * 32768] = f2bf(f);
            float c2v = f, c1v = raw * pb;
#pragma unroll
            for (int m = 1; m <= 32; m <<= 1) {
                c2v += __shfl_xor(c2v, m);
                c1v += __shfl_xor(c1v, m);
            }
            if (lane == 0) {
                atomicAdd(&cvec[bg * 128 + 2 * a], c1v);
                atomicAdd(&cvec[bg * 128 + 2 * a + 1], c2v);
            }
        }
    } else {
        int d = col >> 6, a = col & 63;
        size_t idx0 = ((size_t)((d >> 4) * 2 + (a >> 5)) * 64 +
                       (((a & 31) >> 3) * 16 + (d & 15))) * 8 + (a & 7);
#pragma unroll
        for (int b = 0; b < 16; ++b)
            wufrag[idx0 + (size_t)(bh * 16 + b) * 32768] = f2bf(acc[b]);
    }
}

// ---------------------------------------------------------------------------
// Kernel 2 (round-6): R0 datapath, 2048 blocks x 2 tiles (32 rows/block).
//  * Tile-2's 8 float4 input loads are issued immediately after tile-1's
//    stage consumes the registers (WAR, compiler renames; +32 VGPR bounded
//    by __launch_bounds__(256,4) -> <=128, no spill).  They stay in flight
//    across tile-1's three barriers via raw BAR() (no vmcnt drain) --
//    ~2500 cy of compute covers the HBM latency + queue.
//  * Per-block invariants (coeff, cvec, wd/wu bases, swizzle math)
//    amortized over 2 tiles.
//  * out is write-once-never-read -> __builtin_nontemporal_store, freeing
//    L2 for the input window (epilogue residual re-read) and weights.
//  * bijective XCD swizzle (2048%8==0): XCD x owns 256 blocks = 4 b's.
// LDS 26 KB (6 blocks would fit), VGPR-capped at 4 blocks/CU -- occupancy
// unchanged vs R0. WRITE_SIZE is the spill tripwire.
// ---------------------------------------------------------------------------
__global__ __launch_bounds__(256, 4) void fused_adapter(
    const float* __restrict__ inp,
    const unsigned short* __restrict__ wdfold,
    const unsigned short* __restrict__ wufrag,
    const float* __restrict__ vecs,
    const float* __restrict__ cvec,
    float* __restrict__ out) {
    __shared__ __align__(16) unsigned short z_lds[16][520];
    __shared__ __align__(16) unsigned short mid_lds[16][72];
    __shared__ __align__(16) float coeff[1536];  // post_w | post_b | b_up
    __shared__ __align__(16) float preS[16][4], preQ[16][4];
    __shared__ __align__(16) float postS[16][4], postQ[16][4];

    const int tid = threadIdx.x;
    const int lane = tid & 63;
    const int wave = tid >> 6;
    const int lanelo = lane & 15;
    const int quad = lane >> 4;
    // bijective XCD swizzle: bx0%8 -> XCD, each XCD a contiguous 256-block
    // range = 4 complete b's (weights L2-resident per XCD).
    const int bx0 = blockIdx.x;
    const int bx = (bx0 & 7) * 256 + (bx0 >> 3);
    const int b = bx >> 6;
    const int sgrp = (bx & 63) * 32;     // 32 rows = 2 tiles per block

    // ---- issue tile-0 input loads first (deepest latency) ----
    const float* xpw = inp + ((size_t)b * NS + sgrp + lanelo) * ND + wave * 128 + quad * 8;
    float4 x0[4], x1[4];
#pragma unroll
    for (int kc2 = 0; kc2 < 4; ++kc2) {
        x0[kc2] = *(const float4*)(xpw + kc2 * 32);
        x1[kc2] = *(const float4*)(xpw + kc2 * 32 + 4);
    }

    const float* vb = vecs + b * 2624;
    for (int i = tid; i < 384; i += 256)
        ((float4*)coeff)[i] = ((const float4*)(vb + 1024))[i];

    // per-block invariants (reused by both tiles)
    const unsigned short* wd = wdfold + (size_t)b * 32768;
    const unsigned short* wu = wufrag + (size_t)b * 32768;
    const int a_col = wave * 16 + lanelo;
    const float2 cc = *(const float2*)(cvec + b * 128 + 2 * a_col);
    const float c1 = cc.x + vb[2560 + a_col];

    // stage current x0/x1 registers -> stats + bf16 pack -> z_lds, preS/Q
    auto stage = [&]() {
        float s = 0.f, q = 0.f;
#pragma unroll
        for (int kc2 = 0; kc2 < 4; ++kc2) {
            float4 a = x0[kc2], c = x1[kc2];
            s += (a.x + a.y + a.z + a.w) + (c.x + c.y + c.z + c.w);
            q = fmaf(a.x, a.x, q); q = fmaf(a.y, a.y, q);
            q = fmaf(a.z, a.z, q); q = fmaf(a.w, a.w, q);
            q = fmaf(c.x, c.x, q); q = fmaf(c.y, c.y, q);
            q = fmaf(c.z, c.z, q); q = fmaf(c.w, c.w, q);
            uint4 au;
            au.x = pk(a.x, a.y); au.y = pk(a.z, a.w);
            au.z = pk(c.x, c.y); au.w = pk(c.z, c.w);
            *(uint4*)&z_lds[lanelo][wave * 128 + kc2 * 32 + quad * 8] = au;
        }
        s += __shfl_xor(s, 16); s += __shfl_xor(s, 32);
        q += __shfl_xor(q, 16); q += __shfl_xor(q, 32);
        if (lane < 16) { preS[lane][wave] = s; preQ[lane][wave] = q; }
    };

    // full tile pipeline from post-stage barrier to epilogue (R0 datapath)
    auto do_tile = [&](size_t obase) {
        float rs[4], mrs[4];
#pragma unroll
        for (int r = 0; r < 4; ++r) {
            int row = quad * 4 + r;
            float4 S = *(const float4*)preS[row];
            float4 Q = *(const float4*)preQ[row];
            float ss = (S.x + S.y) + (S.z + S.w);
            float qq = (Q.x + Q.y) + (Q.z + Q.w);
            float mean = ss * (1.0f / 512.0f);
            float var = qq * (1.0f / 512.0f) - mean * mean;
            float rstd = rsqrtf(var + 1e-5f);
            rs[r] = rstd;
            mrs[r] = mean * rstd;
        }

        // ---- phase B: down GEMM, nt = wave ----
        f32x4 accd = (f32x4){0.f, 0.f, 0.f, 0.f};
#pragma unroll
        for (int kc = 0; kc < 16; ++kc) {
            uint4 azu = *(const uint4*)&z_lds[lanelo][kc * 32 + quad * 8];
            uint4 bv = *(const uint4*)(wd + ((size_t)(wave * 16 + kc) * 64 + lane) * 8);
            accd = __builtin_amdgcn_mfma_f32_16x16x32_bf16(
                __builtin_bit_cast(bf16x8, azu), __builtin_bit_cast(bf16x8, bv), accd, 0, 0, 0);
        }
#pragma unroll
        for (int r = 0; r < 4; ++r) {
            float v = fmaf(rs[r], accd[r], fmaf(-mrs[r], cc.y, c1));
            mid_lds[quad * 4 + r][a_col] = f2bf(fmaxf(v, 0.0f));
        }
        BAR();  // mid visible

        // ---- phase C: up GEMM, wave w -> cols [128w,128w+128), acc[8] ----
        uint4 a0u = *(const uint4*)&mid_lds[lanelo][quad * 8];
        uint4 a1u = *(const uint4*)&mid_lds[lanelo][32 + quad * 8];
        bf16x8 af0 = __builtin_bit_cast(bf16x8, a0u);
        bf16x8 af1 = __builtin_bit_cast(bf16x8, a1u);
        f32x4 acc8[8];
        float sum[4] = {0.f, 0.f, 0.f, 0.f}, sq[4] = {0.f, 0.f, 0.f, 0.f};
#pragma unroll
        for (int nt8 = 0; nt8 < 8; ++nt8) {
            int nt = wave * 8 + nt8;
            uint4 b0 = *(const uint4*)(wu + ((size_t)(nt * 2 + 0) * 64 + lane) * 8);
            uint4 b1 = *(const uint4*)(wu + ((size_t)(nt * 2 + 1) * 64 + lane) * 8);
            f32x4 a4 = (f32x4){0.f, 0.f, 0.f, 0.f};
            a4 = __builtin_amdgcn_mfma_f32_16x16x32_bf16(af0, __builtin_bit_cast(bf16x8, b0), a4, 0, 0, 0);
            a4 = __builtin_amdgcn_mfma_f32_16x16x32_bf16(af1, __builtin_bit_cast(bf16x8, b1), a4, 0, 0, 0);
            float bu = coeff[1024 + nt * 16 + lanelo];
#pragma unroll
            for (int r = 0; r < 4; ++r) {
                float y = a4[r] + bu;
                a4[r] = y;
                sum[r] += y;
                sq[r] = fmaf(y, y, sq[r]);
            }
            acc8[nt8] = a4;
        }
#pragma unroll
        for (int r = 0; r < 4; ++r) {
#pragma unroll
            for (int m = 1; m <= 8; m <<= 1) {
                sum[r] += __shfl_xor(sum[r], m);
                sq[r] += __shfl_xor(sq[r], m);
            }
        }
        if (lanelo == 0) {
#pragma unroll
            for (int r = 0; r < 4; ++r) {
                postS[quad * 4 + r][wave] = sum[r];
                postQ[quad * 4 + r][wave] = sq[r];
            }
        }
        BAR();  // post-stat partials visible

        float mean2[4], rstd2[4];
#pragma unroll
        for (int r = 0; r < 4; ++r) {
            int row = quad * 4 + r;
            float4 S = *(const float4*)postS[row];
            float4 Q = *(const float4*)postQ[row];
            float ss = (S.x + S.y) + (S.z + S.w);
            float qq = (Q.x + Q.y) + (Q.z + Q.w);
            mean2[r] = ss * (1.0f / 512.0f);
            float v2 = qq * (1.0f / 512.0f) - mean2[r] * mean2[r];
            rstd2[r] = rsqrtf(v2 + 1e-5f);
        }

        // ---- epilogue: post-LN affine, +x (L2 re-read), nontemporal store ----
#pragma unroll
        for (int nt8 = 0; nt8 < 8; ++nt8) {
            int col = (wave * 8 + nt8) * 16 + lanelo;
            float pw = coeff[col];
            float pb = coeff[512 + col];
#pragma unroll
            for (int r = 0; r < 4; ++r) {
                size_t off = obase + (size_t)(quad * 4 + r) * ND + col;
                float v = fmaf((acc8[nt8][r] - mean2[r]) * rstd2[r], pw, pb) + inp[off];
                __builtin_nontemporal_store(v, &out[off]);
            }
        }
    };

    const size_t obase0 = ((size_t)b * NS + sgrp) * ND;

    // ================= TILE 0 =================
    stage();                              // consumes x0/x1
    {   // prefetch tile 1: regs free after stage; stays in flight across BARs
        const float* xn = xpw + 16 * ND;
#pragma unroll
        for (int kc2 = 0; kc2 < 4; ++kc2) {
            x0[kc2] = *(const float4*)(xn + kc2 * 32);
            x1[kc2] = *(const float4*)(xn + kc2 * 32 + 4);
        }
    }
    BAR();  // z + pre-stats + coeff visible; tile-1 loads outstanding
    do_tile(obase0);
    BAR();  // all z/mid/pre reads of tile 0 done -> safe to restage

    // ================= TILE 1 =================
    stage();                              // compiler waits on prefetch here
    BAR();  // z + pre-stats visible
    do_tile(obase0 + (size_t)16 * ND);
}

// ---------------------------------------------------------------------------
extern "C" void kernel_launch(void* const* d_in, const int* in_sizes, int n_in,
                              void* d_out, int out_size, void* d_ws, size_t ws_size,
                              hipStream_t stream) {
    const float* emb  = (const float*)d_in[0];
    const float* inp  = (const float*)d_in[1];
    const float* dwW  = (const float*)d_in[2];
    const float* dwb  = (const float*)d_in[3];
    const float* dbW  = (const float*)d_in[4];
    const float* dbb  = (const float*)d_in[5];
    const float* uwW  = (const float*)d_in[6];
    const float* uwb  = (const float*)d_in[7];
    const float* ubW  = (const float*)d_in[8];
    const float* ubb  = (const float*)d_in[9];
    const float* pwW  = (const float*)d_in[10];
    const float* pwb  = (const float*)d_in[11];
    const float* pbW  = (const float*)d_in[12];
    const float* pbb  = (const float*)d_in[13];
    const float* powW = (const float*)d_in[14];
    const float* powb = (const float*)d_in[15];
    const float* pobW = (const float*)d_in[16];
    const float* pobb = (const float*)d_in[17];

    unsigned short* wdfrag = (unsigned short*)d_ws;
    unsigned short* wufrag = wdfrag + (size_t)NB * 32768;
    float* vecs = (float*)(wufrag + (size_t)NB * 32768);
    float* cvec = vecs + (size_t)NB * 2624;

    hyper_vec<<<(NB * 2624 + 255) / 256, 256, 0, stream>>>(
        emb, pwW, pwb, pbW, pbb, powW, powb, pobW, pobb, ubW, ubb, dbW, dbb, vecs);
    hipMemsetAsync(cvec, 0, (size_t)NB * 128 * sizeof(float), stream);
    hyper_pack<<<512, 256, 0, stream>>>(emb, dwW, dwb, uwW, uwb, vecs,
                                        wdfrag, wufrag, cvec);
    fused_adapter<<<NB * (NS / 32), 256, 0, stream>>>(
        inp, wdfrag, wufrag, vecs, cvec, (float*)d_out);
}

// Round 7
// 326.223 us; speedup vs baseline: 1.1160x; 1.1094x over previous
//
#include <hip/hip_runtime.h>

#define NB 32
#define NS 2048
#define ND 512
#define NA 64
#define NE 64

typedef __bf16 bf16x8 __attribute__((ext_vector_type(8)));
typedef float f32x4 __attribute__((ext_vector_type(4)));

__device__ __forceinline__ unsigned short f2bf(float f) {
    union { float f; unsigned u; } v; v.f = f;
    unsigned r = (v.u + 0x7fffu + ((v.u >> 16) & 1u)) >> 16;
    return (unsigned short)r;
}
__device__ __forceinline__ unsigned pk(float a, float b) {
    return (unsigned)f2bf(a) | ((unsigned)f2bf(b) << 16);
}

// ---------------------------------------------------------------------------
// Kernel 1b (runs FIRST): six small per-sample vectors, per b:
// [pre_w 512][pre_b 512][post_w 512][post_b 512][b_up 512][b_down 64] = 2624
// Also zeroes cvec inline (replaces the hipMemsetAsync dispatch).
// ---------------------------------------------------------------------------
__global__ __launch_bounds__(256) void hyper_vec(
    const float* __restrict__ emb,
    const float* __restrict__ pwW, const float* __restrict__ pwb,
    const float* __restrict__ pbW, const float* __restrict__ pbb,
    const float* __restrict__ powW, const float* __restrict__ powb,
    const float* __restrict__ pobW, const float* __restrict__ pobb,
    const float* __restrict__ ubW, const float* __restrict__ ubb,
    const float* __restrict__ dbW, const float* __restrict__ dbb,
    float* __restrict__ vecs, float* __restrict__ cvec) {
    int gid = blockIdx.x * 256 + threadIdx.x;
    if (gid < NB * 128) cvec[gid] = 0.0f;          // fused memset
    if (gid >= NB * 2624) return;
    int b = gid / 2624;
    int r = gid - b * 2624;
    const float* W; const float* bias; int off, width;
    if (r < 2560) {
        int v = r >> 9; off = r & 511; width = 512;
        switch (v) {
            case 0:  W = pwW;  bias = pwb;  break;
            case 1:  W = pbW;  bias = pbb;  break;
            case 2:  W = powW; bias = powb; break;
            case 3:  W = pobW; bias = pobb; break;
            default: W = ubW;  bias = ubb;  break;
        }
    } else {
        off = r - 2560; width = 64; W = dbW; bias = dbb;
    }
    float acc = bias[off];
    const float* e = emb + b * 64;
#pragma unroll 8
    for (int k = 0; k < 64; ++k) acc = fmaf(e[k], W[k * width + off], acc);
    vecs[gid] = acc;
}

// ---------------------------------------------------------------------------
// Kernel 1a (round-7): hypernet big GEMMs emb[32,64] @ W[64,32768] -> bf16
// frags.  4x more parallel than before: 2048 blocks, each handles 8 b's
// (bq = bx&3 selects b-octet) x one 128-col chunk of one matrix.
// Per-thread main loop 1024 -> 256 FMA; tail (shfl chains, scattered
// stores, atomics) 16 -> 4 iterations.  Index math is UNCHANGED.
// mat==0 (down): fold pre-LN weight (f = raw*pre_w), emit folded frags and
//   atomically accumulate c1/c2 into cvec.  mat==1 (up): plain frags.
// ---------------------------------------------------------------------------
__global__ __launch_bounds__(256) void hyper_pack(
    const float* __restrict__ emb,
    const float* __restrict__ dwW, const float* __restrict__ dwb,
    const float* __restrict__ uwW, const float* __restrict__ uwb,
    const float* __restrict__ vecs,
    unsigned short* __restrict__ wdfrag, unsigned short* __restrict__ wufrag,
    float* __restrict__ cvec) {
    __shared__ float Wt[64][128];
    __shared__ float embs[8 * NE];
    const int tid = threadIdx.x;
    const int lane = tid & 63;
    const int bx = blockIdx.x;
    const int mat = bx >> 10;           // 0: down, 1: up
    const int chunk = (bx >> 2) & 255;
    const int bq = bx & 3;              // b-octet [8*bq, 8*bq+8)
    const int base = chunk * 128;
    const int colo = tid & 127;
    const int bh = tid >> 7;            // 0/1: local b-range [4*bh, 4*bh+4)
    const float* W = mat ? uwW : dwW;
    const float* bias = mat ? uwb : dwb;

    for (int i = tid; i < 8 * NE; i += 256) embs[i] = emb[bq * 8 * 64 + i];
    for (int i = tid; i < 64 * 32; i += 256) {
        int k = i >> 5, c = (i & 31) << 2;
        *(float4*)&Wt[k][c] = *(const float4*)&W[(size_t)k * 32768 + base + c];
    }
    __syncthreads();

    const int col = base + colo;
    const float bv = bias[col];
    float acc[4];
#pragma unroll
    for (int lb = 0; lb < 4; ++lb) acc[lb] = bv;

    for (int k0 = 0; k0 < 64; k0 += 4) {
        float w0 = Wt[k0][colo], w1 = Wt[k0 + 1][colo];
        float w2 = Wt[k0 + 2][colo], w3 = Wt[k0 + 3][colo];
#pragma unroll
        for (int lb = 0; lb < 4; ++lb) {
            float4 e = *(const float4*)&embs[(bh * 4 + lb) * 64 + k0];
            acc[lb] = fmaf(e.x, w0, acc[lb]);
            acc[lb] = fmaf(e.y, w1, acc[lb]);
            acc[lb] = fmaf(e.z, w2, acc[lb]);
            acc[lb] = fmaf(e.w, w3, acc[lb]);
        }
    }

    if (mat == 0) {
        int a = col >> 9, d = col & 511;   // a uniform per block (128 | 512)
        size_t idx0 = ((size_t)((a >> 4) * 16 + (d >> 5)) * 64 +
                       (((d & 31) >> 3) * 16 + (a & 15))) * 8 + (d & 7);
#pragma unroll
        for (int lb = 0; lb < 4; ++lb) {
            int bg = bq * 8 + bh * 4 + lb;
            float raw = acc[lb];
            float pw = vecs[bg * 2624 + d];
            float pb = vecs[bg * 2624 + 512 + d];
            float f = raw * pw;
            wdfrag[idx0 + (size_t)bg * 32768] = f2bf(f);
            float c2v = f, c1v = raw * pb;
#pragma unroll
            for (int m = 1; m <= 32; m <<= 1) {
                c2v += __shfl_xor(c2v, m);
                c1v += __shfl_xor(c1v, m);
            }
            if (lane == 0) {
                atomicAdd(&cvec[bg * 128 + 2 * a], c1v);
                atomicAdd(&cvec[bg * 128 + 2 * a + 1], c2v);
            }
        }
    } else {
        int d = col >> 6, a = col & 63;
        size_t idx0 = ((size_t)((d >> 4) * 2 + (a >> 5)) * 64 +
                       (((a & 31) >> 3) * 16 + (d & 15))) * 8 + (a & 7);
#pragma unroll
        for (int lb = 0; lb < 4; ++lb)
            wufrag[idx0 + (size_t)(bq * 8 + bh * 4 + lb) * 32768] = f2bf(acc[lb]);
    }
}

// ---------------------------------------------------------------------------
// Kernel 2: EXACT round-0 fused adapter (best measured: 100.3 us).
// [foldedLN + down MFMA] -> relu -> up (MFMA, col-split) -> postLN -> +x.
// 4096 blocks x 256 threads; block = (b, 16-row S-tile).
// ---------------------------------------------------------------------------
__global__ __launch_bounds__(256, 5) void fused_adapter(
    const float* __restrict__ inp,
    const unsigned short* __restrict__ wdfold,
    const unsigned short* __restrict__ wufrag,
    const float* __restrict__ vecs,
    const float* __restrict__ cvec,
    float* __restrict__ out) {
    __shared__ __align__(16) unsigned short z_lds[16][520];
    __shared__ __align__(16) unsigned short mid_lds[16][72];
    __shared__ __align__(16) float coeff[1536];  // post_w | post_b | b_up
    __shared__ __align__(16) float preS[16][4], preQ[16][4];
    __shared__ __align__(16) float postS[16][4], postQ[16][4];

    const int tid = threadIdx.x;
    const int lane = tid & 63;
    const int wave = tid >> 6;
    const int lanelo = lane & 15;
    const int quad = lane >> 4;
    const int bx = blockIdx.x;
    const int b = bx >> 7;
    const int s0 = (bx & 127) * 16;

    const float* vb = vecs + b * 2624;
    for (int i = tid; i < 384; i += 256)
        ((float4*)coeff)[i] = ((const float4*)(vb + 1024))[i];

    // ---- Phase A: wave w loads cols [128w,128w+128) of the 16 rows ----
    const float* xp = inp + ((size_t)b * NS + s0 + lanelo) * ND + wave * 128 + quad * 8;
    float s = 0.f, q = 0.f;
#pragma unroll
    for (int kc2 = 0; kc2 < 4; ++kc2) {
        float4 x0 = *(const float4*)(xp + kc2 * 32);
        float4 x1 = *(const float4*)(xp + kc2 * 32 + 4);
        s += (x0.x + x0.y + x0.z + x0.w) + (x1.x + x1.y + x1.z + x1.w);
        q = fmaf(x0.x, x0.x, q); q = fmaf(x0.y, x0.y, q);
        q = fmaf(x0.z, x0.z, q); q = fmaf(x0.w, x0.w, q);
        q = fmaf(x1.x, x1.x, q); q = fmaf(x1.y, x1.y, q);
        q = fmaf(x1.z, x1.z, q); q = fmaf(x1.w, x1.w, q);
        uint4 au;
        au.x = pk(x0.x, x0.y); au.y = pk(x0.z, x0.w);
        au.z = pk(x1.x, x1.y); au.w = pk(x1.z, x1.w);
        *(uint4*)&z_lds[lanelo][wave * 128 + kc2 * 32 + quad * 8] = au;
    }
    s += __shfl_xor(s, 16); s += __shfl_xor(s, 32);
    q += __shfl_xor(q, 16); q += __shfl_xor(q, 32);
    if (lane < 16) { preS[lane][wave] = s; preQ[lane][wave] = q; }
    __syncthreads();  // z + pre-stat partials + coeff visible

    float rs[4], mrs[4];
#pragma unroll
    for (int r = 0; r < 4; ++r) {
        int row = quad * 4 + r;
        float4 S = *(const float4*)preS[row];
        float4 Q = *(const float4*)preQ[row];
        float ss = (S.x + S.y) + (S.z + S.w);
        float qq = (Q.x + Q.y) + (Q.z + Q.w);
        float mean = ss * (1.0f / 512.0f);
        float var = qq * (1.0f / 512.0f) - mean * mean;
        float rstd = rsqrtf(var + 1e-5f);
        rs[r] = rstd;
        mrs[r] = mean * rstd;
    }

    // ---- Phase B: down GEMM, nt = wave; acc is one f32x4 ----
    const unsigned short* wd = wdfold + (size_t)b * 32768;
    f32x4 accd = (f32x4){0.f, 0.f, 0.f, 0.f};
#pragma unroll
    for (int kc = 0; kc < 16; ++kc) {
        uint4 au = *(const uint4*)&z_lds[lanelo][kc * 32 + quad * 8];
        uint4 bu = *(const uint4*)(wd + ((size_t)(wave * 16 + kc) * 64 + lane) * 8);
        accd = __builtin_amdgcn_mfma_f32_16x16x32_bf16(
            __builtin_bit_cast(bf16x8, au), __builtin_bit_cast(bf16x8, bu), accd, 0, 0, 0);
    }
    const int a_col = wave * 16 + lanelo;
    float2 cc = *(const float2*)(cvec + b * 128 + 2 * a_col);
    float c1 = cc.x + vb[2560 + a_col];
#pragma unroll
    for (int r = 0; r < 4; ++r) {
        float v = fmaf(rs[r], accd[r], fmaf(-mrs[r], cc.y, c1));
        mid_lds[quad * 4 + r][a_col] = f2bf(fmaxf(v, 0.0f));
    }
    __syncthreads();  // mid visible

    // ---- Phase C: up GEMM, wave w -> cols [128w,128w+128), acc[8] ----
    uint4 a0u = *(const uint4*)&mid_lds[lanelo][quad * 8];
    uint4 a1u = *(const uint4*)&mid_lds[lanelo][32 + quad * 8];
    bf16x8 af0 = __builtin_bit_cast(bf16x8, a0u);
    bf16x8 af1 = __builtin_bit_cast(bf16x8, a1u);
    const unsigned short* wu = wufrag + (size_t)b * 32768;
    f32x4 acc8[8];
    float sum[4] = {0.f, 0.f, 0.f, 0.f}, sq[4] = {0.f, 0.f, 0.f, 0.f};
#pragma unroll
    for (int nt8 = 0; nt8 < 8; ++nt8) {
        int nt = wave * 8 + nt8;
        uint4 b0 = *(const uint4*)(wu + ((size_t)(nt * 2 + 0) * 64 + lane) * 8);
        uint4 b1 = *(const uint4*)(wu + ((size_t)(nt * 2 + 1) * 64 + lane) * 8);
        f32x4 a4 = (f32x4){0.f, 0.f, 0.f, 0.f};
        a4 = __builtin_amdgcn_mfma_f32_16x16x32_bf16(af0, __builtin_bit_cast(bf16x8, b0), a4, 0, 0, 0);
        a4 = __builtin_amdgcn_mfma_f32_16x16x32_bf16(af1, __builtin_bit_cast(bf16x8, b1), a4, 0, 0, 0);
        float bu = coeff[1024 + nt * 16 + lanelo];
#pragma unroll
        for (int r = 0; r < 4; ++r) {
            float y = a4[r] + bu;
            a4[r] = y;
            sum[r] += y;
            sq[r] = fmaf(y, y, sq[r]);
        }
        acc8[nt8] = a4;
    }
#pragma unroll
    for (int r = 0; r < 4; ++r) {
#pragma unroll
        for (int m = 1; m <= 8; m <<= 1) {
            sum[r] += __shfl_xor(sum[r], m);
            sq[r] += __shfl_xor(sq[r], m);
        }
    }
    if (lanelo == 0) {
#pragma unroll
        for (int r = 0; r < 4; ++r) {
            postS[quad * 4 + r][wave] = sum[r];
            postQ[quad * 4 + r][wave] = sq[r];
        }
    }
    __syncthreads();  // post-stat partials visible

    float mean2[4], rstd2[4];
#pragma unroll
    for (int r = 0; r < 4; ++r) {
        int row = quad * 4 + r;
        float4 S = *(const float4*)postS[row];
        float4 Q = *(const float4*)postQ[row];
        float ss = (S.x + S.y) + (S.z + S.w);
        float qq = (Q.x + Q.y) + (Q.z + Q.w);
        mean2[r] = ss * (1.0f / 512.0f);
        float v2 = qq * (1.0f / 512.0f) - mean2[r] * mean2[r];
        rstd2[r] = rsqrtf(v2 + 1e-5f);
    }

    // ---- epilogue: post-LN affine, +x, store ----
    const size_t obase = ((size_t)b * NS + s0) * ND;
#pragma unroll
    for (int nt8 = 0; nt8 < 8; ++nt8) {
        int col = (wave * 8 + nt8) * 16 + lanelo;
        float pw = coeff[col];
        float pb = coeff[512 + col];
#pragma unroll
        for (int r = 0; r < 4; ++r) {
            size_t off = obase + (size_t)(quad * 4 + r) * ND + col;
            out[off] = fmaf((acc8[nt8][r] - mean2[r]) * rstd2[r], pw, pb) + inp[off];
        }
    }
}

// ---------------------------------------------------------------------------
extern "C" void kernel_launch(void* const* d_in, const int* in_sizes, int n_in,
                              void* d_out, int out_size, void* d_ws, size_t ws_size,
                              hipStream_t stream) {
    const float* emb  = (const float*)d_in[0];
    const float* inp  = (const float*)d_in[1];
    const float* dwW  = (const float*)d_in[2];
    const float* dwb  = (const float*)d_in[3];
    const float* dbW  = (const float*)d_in[4];
    const float* dbb  = (const float*)d_in[5];
    const float* uwW  = (const float*)d_in[6];
    const float* uwb  = (const float*)d_in[7];
    const float* ubW  = (const float*)d_in[8];
    const float* ubb  = (const float*)d_in[9];
    const float* pwW  = (const float*)d_in[10];
    const float* pwb  = (const float*)d_in[11];
    const float* pbW  = (const float*)d_in[12];
    const float* pbb  = (const float*)d_in[13];
    const float* powW = (const float*)d_in[14];
    const float* powb = (const float*)d_in[15];
    const float* pobW = (const float*)d_in[16];
    const float* pobb = (const float*)d_in[17];

    unsigned short* wdfrag = (unsigned short*)d_ws;
    unsigned short* wufrag = wdfrag + (size_t)NB * 32768;
    float* vecs = (float*)(wufrag + (size_t)NB * 32768);
    float* cvec = vecs + (size_t)NB * 2624;

    hyper_vec<<<(NB * 2624 + 255) / 256, 256, 0, stream>>>(
        emb, pwW, pwb, pbW, pbb, powW, powb, pobW, pobb, ubW, ubb, dbW, dbb,
        vecs, cvec);
    hyper_pack<<<2048, 256, 0, stream>>>(emb, dwW, dwb, uwW, uwb, vecs,
                                         wdfrag, wufrag, cvec);
    fused_adapter<<<NB * (NS / 16), 256, 0, stream>>>(
        inp, wdfrag, wufrag, vecs, cvec, (float*)d_out);
}

// Round 8
// 322.351 us; speedup vs baseline: 1.1294x; 1.0120x over previous
//
#include <hip/hip_runtime.h>

#define NB 32
#define NS 2048
#define ND 512
#define NA 64
#define NE 64

typedef __bf16 bf16x8 __attribute__((ext_vector_type(8)));
typedef float f32x4 __attribute__((ext_vector_type(4)));

__device__ __forceinline__ unsigned short f2bf(float f) {
    union { float f; unsigned u; } v; v.f = f;
    unsigned r = (v.u + 0x7fffu + ((v.u >> 16) & 1u)) >> 16;
    return (unsigned short)r;
}
__device__ __forceinline__ unsigned pk(float a, float b) {
    return (unsigned)f2bf(a) | ((unsigned)f2bf(b) << 16);
}

// ---------------------------------------------------------------------------
// Kernel 1b (runs FIRST): six small per-sample vectors, per b:
// [pre_w 512][pre_b 512][post_w 512][post_b 512][b_up 512][b_down 64] = 2624
// Also zeroes cvec inline (replaces the hipMemsetAsync dispatch).
// ---------------------------------------------------------------------------
__global__ __launch_bounds__(256) void hyper_vec(
    const float* __restrict__ emb,
    const float* __restrict__ pwW, const float* __restrict__ pwb,
    const float* __restrict__ pbW, const float* __restrict__ pbb,
    const float* __restrict__ powW, const float* __restrict__ powb,
    const float* __restrict__ pobW, const float* __restrict__ pobb,
    const float* __restrict__ ubW, const float* __restrict__ ubb,
    const float* __restrict__ dbW, const float* __restrict__ dbb,
    float* __restrict__ vecs, float* __restrict__ cvec) {
    int gid = blockIdx.x * 256 + threadIdx.x;
    if (gid < NB * 128) cvec[gid] = 0.0f;          // fused memset
    if (gid >= NB * 2624) return;
    int b = gid / 2624;
    int r = gid - b * 2624;
    const float* W; const float* bias; int off, width;
    if (r < 2560) {
        int v = r >> 9; off = r & 511; width = 512;
        switch (v) {
            case 0:  W = pwW;  bias = pwb;  break;
            case 1:  W = pbW;  bias = pbb;  break;
            case 2:  W = powW; bias = powb; break;
            case 3:  W = pobW; bias = pobb; break;
            default: W = ubW;  bias = ubb;  break;
        }
    } else {
        off = r - 2560; width = 64; W = dbW; bias = dbb;
    }
    float acc = bias[off];
    const float* e = emb + b * 64;
#pragma unroll 8
    for (int k = 0; k < 64; ++k) acc = fmaf(e[k], W[k * width + off], acc);
    vecs[gid] = acc;
}

// ---------------------------------------------------------------------------
// Kernel 1a: hypernet big GEMMs emb[32,64] @ W[64,32768] -> bf16 frags.
// (round-7 4x-parallel version: 2048 blocks, 8 b's per block; kept as-is)
// ---------------------------------------------------------------------------
__global__ __launch_bounds__(256) void hyper_pack(
    const float* __restrict__ emb,
    const float* __restrict__ dwW, const float* __restrict__ dwb,
    const float* __restrict__ uwW, const float* __restrict__ uwb,
    const float* __restrict__ vecs,
    unsigned short* __restrict__ wdfrag, unsigned short* __restrict__ wufrag,
    float* __restrict__ cvec) {
    __shared__ float Wt[64][128];
    __shared__ float embs[8 * NE];
    const int tid = threadIdx.x;
    const int lane = tid & 63;
    const int bx = blockIdx.x;
    const int mat = bx >> 10;           // 0: down, 1: up
    const int chunk = (bx >> 2) & 255;
    const int bq = bx & 3;              // b-octet [8*bq, 8*bq+8)
    const int base = chunk * 128;
    const int colo = tid & 127;
    const int bh = tid >> 7;            // 0/1: local b-range [4*bh, 4*bh+4)
    const float* W = mat ? uwW : dwW;
    const float* bias = mat ? uwb : dwb;

    for (int i = tid; i < 8 * NE; i += 256) embs[i] = emb[bq * 8 * 64 + i];
    for (int i = tid; i < 64 * 32; i += 256) {
        int k = i >> 5, c = (i & 31) << 2;
        *(float4*)&Wt[k][c] = *(const float4*)&W[(size_t)k * 32768 + base + c];
    }
    __syncthreads();

    const int col = base + colo;
    const float bv = bias[col];
    float acc[4];
#pragma unroll
    for (int lb = 0; lb < 4; ++lb) acc[lb] = bv;

    for (int k0 = 0; k0 < 64; k0 += 4) {
        float w0 = Wt[k0][colo], w1 = Wt[k0 + 1][colo];
        float w2 = Wt[k0 + 2][colo], w3 = Wt[k0 + 3][colo];
#pragma unroll
        for (int lb = 0; lb < 4; ++lb) {
            float4 e = *(const float4*)&embs[(bh * 4 + lb) * 64 + k0];
            acc[lb] = fmaf(e.x, w0, acc[lb]);
            acc[lb] = fmaf(e.y, w1, acc[lb]);
            acc[lb] = fmaf(e.z, w2, acc[lb]);
            acc[lb] = fmaf(e.w, w3, acc[lb]);
        }
    }

    if (mat == 0) {
        int a = col >> 9, d = col & 511;   // a uniform per block (128 | 512)
        size_t idx0 = ((size_t)((a >> 4) * 16 + (d >> 5)) * 64 +
                       (((d & 31) >> 3) * 16 + (a & 15))) * 8 + (d & 7);
#pragma unroll
        for (int lb = 0; lb < 4; ++lb) {
            int bg = bq * 8 + bh * 4 + lb;
            float raw = acc[lb];
            float pw = vecs[bg * 2624 + d];
            float pb = vecs[bg * 2624 + 512 + d];
            float f = raw * pw;
            wdfrag[idx0 + (size_t)bg * 32768] = f2bf(f);
            float c2v = f, c1v = raw * pb;
#pragma unroll
            for (int m = 1; m <= 32; m <<= 1) {
                c2v += __shfl_xor(c2v, m);
                c1v += __shfl_xor(c1v, m);
            }
            if (lane == 0) {
                atomicAdd(&cvec[bg * 128 + 2 * a], c1v);
                atomicAdd(&cvec[bg * 128 + 2 * a + 1], c2v);
            }
        }
    } else {
        int d = col >> 6, a = col & 63;
        size_t idx0 = ((size_t)((d >> 4) * 2 + (a >> 5)) * 64 +
                       (((a & 31) >> 3) * 16 + (d & 15))) * 8 + (a & 7);
#pragma unroll
        for (int lb = 0; lb < 4; ++lb)
            wufrag[idx0 + (size_t)(bq * 8 + bh * 4 + lb) * 32768] = f2bf(acc[lb]);
    }
}

// ---------------------------------------------------------------------------
// Kernel 2 (round-8): R0 datapath with coeff-LDS shrunk for occupancy.
//  * post_w/post_b -> 16 per-thread registers (block-invariant; each thread
//    only ever uses its 8 columns).  b_up -> 2 KB LDS array (bup).
//  * LDS 26112 -> 22016 B => 7 blocks/CU (was 6 theoretical / ~4 effective).
//  * __launch_bounds__(256, 8) pins VGPR <= 64 (the occupancy quantum step
//    from m68/m69) so 28 waves/CU is actually reachable.  Predicted VGPR
//    ~60.  Spill tripwire: WRITE_SIZE inflation.
// Everything else is bit-identical to the measured-best R0 structure.
// ---------------------------------------------------------------------------
__global__ __launch_bounds__(256, 8) void fused_adapter(
    const float* __restrict__ inp,
    const unsigned short* __restrict__ wdfold,
    const unsigned short* __restrict__ wufrag,
    const float* __restrict__ vecs,
    const float* __restrict__ cvec,
    float* __restrict__ out) {
    __shared__ __align__(16) unsigned short z_lds[16][520];
    __shared__ __align__(16) unsigned short mid_lds[16][72];
    __shared__ __align__(16) float bup[512];     // b_up only (2 KB)
    __shared__ __align__(16) float preS[16][4], preQ[16][4];
    __shared__ __align__(16) float postS[16][4], postQ[16][4];

    const int tid = threadIdx.x;
    const int lane = tid & 63;
    const int wave = tid >> 6;
    const int lanelo = lane & 15;
    const int quad = lane >> 4;
    const int bx = blockIdx.x;
    const int b = bx >> 7;
    const int s0 = (bx & 127) * 16;

    const float* vb = vecs + b * 2624;
    // b_up -> LDS (2 KB); post_w/post_b -> registers (16, block-invariant)
    for (int i = tid; i < 128; i += 256)
        ((float4*)bup)[i] = ((const float4*)(vb + 2048))[i];
    float pw8[8], pb8[8];
#pragma unroll
    for (int i = 0; i < 8; ++i) {
        int col = (wave * 8 + i) * 16 + lanelo;
        pw8[i] = vb[1024 + col];
        pb8[i] = vb[1536 + col];
    }

    // ---- Phase A: wave w loads cols [128w,128w+128) of the 16 rows ----
    const float* xp = inp + ((size_t)b * NS + s0 + lanelo) * ND + wave * 128 + quad * 8;
    float s = 0.f, q = 0.f;
#pragma unroll
    for (int kc2 = 0; kc2 < 4; ++kc2) {
        float4 x0 = *(const float4*)(xp + kc2 * 32);
        float4 x1 = *(const float4*)(xp + kc2 * 32 + 4);
        s += (x0.x + x0.y + x0.z + x0.w) + (x1.x + x1.y + x1.z + x1.w);
        q = fmaf(x0.x, x0.x, q); q = fmaf(x0.y, x0.y, q);
        q = fmaf(x0.z, x0.z, q); q = fmaf(x0.w, x0.w, q);
        q = fmaf(x1.x, x1.x, q); q = fmaf(x1.y, x1.y, q);
        q = fmaf(x1.z, x1.z, q); q = fmaf(x1.w, x1.w, q);
        uint4 au;
        au.x = pk(x0.x, x0.y); au.y = pk(x0.z, x0.w);
        au.z = pk(x1.x, x1.y); au.w = pk(x1.z, x1.w);
        *(uint4*)&z_lds[lanelo][wave * 128 + kc2 * 32 + quad * 8] = au;
    }
    s += __shfl_xor(s, 16); s += __shfl_xor(s, 32);
    q += __shfl_xor(q, 16); q += __shfl_xor(q, 32);
    if (lane < 16) { preS[lane][wave] = s; preQ[lane][wave] = q; }
    __syncthreads();  // z + pre-stat partials + bup visible

    float rs[4], mrs[4];
#pragma unroll
    for (int r = 0; r < 4; ++r) {
        int row = quad * 4 + r;
        float4 S = *(const float4*)preS[row];
        float4 Q = *(const float4*)preQ[row];
        float ss = (S.x + S.y) + (S.z + S.w);
        float qq = (Q.x + Q.y) + (Q.z + Q.w);
        float mean = ss * (1.0f / 512.0f);
        float var = qq * (1.0f / 512.0f) - mean * mean;
        float rstd = rsqrtf(var + 1e-5f);
        rs[r] = rstd;
        mrs[r] = mean * rstd;
    }

    // ---- Phase B: down GEMM, nt = wave; acc is one f32x4 ----
    const unsigned short* wd = wdfold + (size_t)b * 32768;
    f32x4 accd = (f32x4){0.f, 0.f, 0.f, 0.f};
#pragma unroll
    for (int kc = 0; kc < 16; ++kc) {
        uint4 au = *(const uint4*)&z_lds[lanelo][kc * 32 + quad * 8];
        uint4 bu = *(const uint4*)(wd + ((size_t)(wave * 16 + kc) * 64 + lane) * 8);
        accd = __builtin_amdgcn_mfma_f32_16x16x32_bf16(
            __builtin_bit_cast(bf16x8, au), __builtin_bit_cast(bf16x8, bu), accd, 0, 0, 0);
    }
    const int a_col = wave * 16 + lanelo;
    float2 cc = *(const float2*)(cvec + b * 128 + 2 * a_col);
    float c1 = cc.x + vb[2560 + a_col];
#pragma unroll
    for (int r = 0; r < 4; ++r) {
        float v = fmaf(rs[r], accd[r], fmaf(-mrs[r], cc.y, c1));
        mid_lds[quad * 4 + r][a_col] = f2bf(fmaxf(v, 0.0f));
    }
    __syncthreads();  // mid visible

    // ---- Phase C: up GEMM, wave w -> cols [128w,128w+128), acc[8] ----
    uint4 a0u = *(const uint4*)&mid_lds[lanelo][quad * 8];
    uint4 a1u = *(const uint4*)&mid_lds[lanelo][32 + quad * 8];
    bf16x8 af0 = __builtin_bit_cast(bf16x8, a0u);
    bf16x8 af1 = __builtin_bit_cast(bf16x8, a1u);
    const unsigned short* wu = wufrag + (size_t)b * 32768;
    f32x4 acc8[8];
    float sum[4] = {0.f, 0.f, 0.f, 0.f}, sq[4] = {0.f, 0.f, 0.f, 0.f};
#pragma unroll
    for (int nt8 = 0; nt8 < 8; ++nt8) {
        int nt = wave * 8 + nt8;
        uint4 b0 = *(const uint4*)(wu + ((size_t)(nt * 2 + 0) * 64 + lane) * 8);
        uint4 b1 = *(const uint4*)(wu + ((size_t)(nt * 2 + 1) * 64 + lane) * 8);
        f32x4 a4 = (f32x4){0.f, 0.f, 0.f, 0.f};
        a4 = __builtin_amdgcn_mfma_f32_16x16x32_bf16(af0, __builtin_bit_cast(bf16x8, b0), a4, 0, 0, 0);
        a4 = __builtin_amdgcn_mfma_f32_16x16x32_bf16(af1, __builtin_bit_cast(bf16x8, b1), a4, 0, 0, 0);
        float bu = bup[nt * 16 + lanelo];
#pragma unroll
        for (int r = 0; r < 4; ++r) {
            float y = a4[r] + bu;
            a4[r] = y;
            sum[r] += y;
            sq[r] = fmaf(y, y, sq[r]);
        }
        acc8[nt8] = a4;
    }
#pragma unroll
    for (int r = 0; r < 4; ++r) {
#pragma unroll
        for (int m = 1; m <= 8; m <<= 1) {
            sum[r] += __shfl_xor(sum[r], m);
            sq[r] += __shfl_xor(sq[r], m);
        }
    }
    if (lanelo == 0) {
#pragma unroll
        for (int r = 0; r < 4; ++r) {
            postS[quad * 4 + r][wave] = sum[r];
            postQ[quad * 4 + r][wave] = sq[r];
        }
    }
    __syncthreads();  // post-stat partials visible

    float mean2[4], rstd2[4];
#pragma unroll
    for (int r = 0; r < 4; ++r) {
        int row = quad * 4 + r;
        float4 S = *(const float4*)postS[row];
        float4 Q = *(const float4*)postQ[row];
        float ss = (S.x + S.y) + (S.z + S.w);
        float qq = (Q.x + Q.y) + (Q.z + Q.w);
        mean2[r] = ss * (1.0f / 512.0f);
        float v2 = qq * (1.0f / 512.0f) - mean2[r] * mean2[r];
        rstd2[r] = rsqrtf(v2 + 1e-5f);
    }

    // ---- epilogue: post-LN affine (reg coeffs), +x, store ----
    const size_t obase = ((size_t)b * NS + s0) * ND;
#pragma unroll
    for (int nt8 = 0; nt8 < 8; ++nt8) {
        int col = (wave * 8 + nt8) * 16 + lanelo;
#pragma unroll
        for (int r = 0; r < 4; ++r) {
            size_t off = obase + (size_t)(quad * 4 + r) * ND + col;
            out[off] = fmaf((acc8[nt8][r] - mean2[r]) * rstd2[r],
                            pw8[nt8], pb8[nt8]) + inp[off];
        }
    }
}

// ---------------------------------------------------------------------------
extern "C" void kernel_launch(void* const* d_in, const int* in_sizes, int n_in,
                              void* d_out, int out_size, void* d_ws, size_t ws_size,
                              hipStream_t stream) {
    const float* emb  = (const float*)d_in[0];
    const float* inp  = (const float*)d_in[1];
    const float* dwW  = (const float*)d_in[2];
    const float* dwb  = (const float*)d_in[3];
    const float* dbW  = (const float*)d_in[4];
    const float* dbb  = (const float*)d_in[5];
    const float* uwW  = (const float*)d_in[6];
    const float* uwb  = (const float*)d_in[7];
    const float* ubW  = (const float*)d_in[8];
    const float* ubb  = (const float*)d_in[9];
    const float* pwW  = (const float*)d_in[10];
    const float* pwb  = (const float*)d_in[11];
    const float* pbW  = (const float*)d_in[12];
    const float* pbb  = (const float*)d_in[13];
    const float* powW = (const float*)d_in[14];
    const float* powb = (const float*)d_in[15];
    const float* pobW = (const float*)d_in[16];
    const float* pobb = (const float*)d_in[17];

    unsigned short* wdfrag = (unsigned short*)d_ws;
    unsigned short* wufrag = wdfrag + (size_t)NB * 32768;
    float* vecs = (float*)(wufrag + (size_t)NB * 32768);
    float* cvec = vecs + (size_t)NB * 2624;

    hyper_vec<<<(NB * 2624 + 255) / 256, 256, 0, stream>>>(
        emb, pwW, pwb, pbW, pbb, powW, powb, pobW, pobb, ubW, ubb, dbW, dbb,
        vecs, cvec);
    hyper_pack<<<2048, 256, 0, stream>>>(emb, dwW, dwb, uwW, uwb, vecs,
                                         wdfrag, wufrag, cvec);
    fused_adapter<<<NB * (NS / 16), 256, 0, stream>>>(
        inp, wdfrag, wufrag, vecs, cvec, (float*)d_out);
}